// Round 6
// baseline (159.546 us; speedup 1.0000x reference)
//
#include <hip/hip_runtime.h>
#include <math.h>

// Deformation4D: N=1M gaussians, K_NB=10 neighbors, K_TOTAL=300 control points.
//
// v7: non-temporal streaming. Ledger: six variants (43.4-46us) varied LDS
// bytes, bank conflicts, VMEM request shape, occupancy, wave count, per-thread
// ILP, software pipelining -- all neutral, no pipe >25% busy. LLC-inclusive
// traffic is 136MB in 44us = 3.1 TB/s = ~49% of copy ceiling => the wall is
// line throughput in the L1 path: ~6.6K unique never-reused lines/CU transit
// the L1 miss-tracking machinery regardless of request shape. All in/out
// streams here are strictly single-use, so mark them non-temporal
// (__builtin_nontemporal_*) to bypass L1 allocation and ride the L2 path.
//
// Kept (measured-best config): monomial algebra (gather q(16B)+b(16B) per
// neighbor, rebuild sum(wR) in epilogue), 16B-stride de-interleaved LDS table
// (8 bank-groups), 1 gaussian/thread, full grid, fused table build.

typedef float f32x2 __attribute__((ext_vector_type(2)));
typedef float f32x4 __attribute__((ext_vector_type(4)));
typedef int   i32x2 __attribute__((ext_vector_type(2)));

struct Accum {
    float W;
    float Mxx, Myy, Mzz, Mxy, Mxz, Myz, Mwx, Mwy, Mwz;
    float qsw, qsx, qsy, qsz;
    float bsx, bsy, bsz;
};

__device__ __forceinline__ void acc_init(Accum& a) {
    a.W = 0.0f;
    a.Mxx = a.Myy = a.Mzz = 0.0f;
    a.Mxy = a.Mxz = a.Myz = 0.0f;
    a.Mwx = a.Mwy = a.Mwz = 0.0f;
    a.qsw = a.qsx = a.qsy = a.qsz = 0.0f;
    a.bsx = a.bsy = a.bsz = 0.0f;
}

__device__ __forceinline__ void acc_neighbor(Accum& a, const float4* __restrict__ tbl,
                                             int K_TOTAL, int cp, float w) {
    float4 q = tbl[cp];             // (w,x,y,z) normalized; 16B stride
    float4 b = tbl[K_TOTAL + cp];   // (bx,by,bz,_)
    float tw = w * q.x, tx = w * q.y, ty = w * q.z, tz = w * q.w;
    a.W += w;
    a.Mxx = fmaf(tx, q.y, a.Mxx);
    a.Myy = fmaf(ty, q.z, a.Myy);
    a.Mzz = fmaf(tz, q.w, a.Mzz);
    a.Mxy = fmaf(tx, q.z, a.Mxy);
    a.Mxz = fmaf(tx, q.w, a.Mxz);
    a.Myz = fmaf(ty, q.w, a.Myz);
    a.Mwx = fmaf(tw, q.y, a.Mwx);
    a.Mwy = fmaf(tw, q.z, a.Mwy);
    a.Mwz = fmaf(tw, q.w, a.Mwz);
    a.qsw += tw; a.qsx += tx; a.qsy += ty; a.qsz += tz;
    a.bsx = fmaf(w, b.x, a.bsx);
    a.bsy = fmaf(w, b.y, a.bsy);
    a.bsz = fmaf(w, b.z, a.bsz);
}

__device__ __forceinline__ void acc_epilogue(const Accum& a,
                                             float mx, float my, float mz,
                                             float gw, float gx, float gy, float gz,
                                             float* dmx, float* dmy, float* dmz,
                                             f32x4* oq) {
    float A00 = a.W - 2.0f * (a.Myy + a.Mzz);
    float A01 = 2.0f * (a.Mxy - a.Mwz);
    float A02 = 2.0f * (a.Mxz + a.Mwy);
    float A10 = 2.0f * (a.Mxy + a.Mwz);
    float A11 = a.W - 2.0f * (a.Mxx + a.Mzz);
    float A12 = 2.0f * (a.Myz - a.Mwx);
    float A20 = 2.0f * (a.Mxz - a.Mwy);
    float A21 = 2.0f * (a.Myz + a.Mwx);
    float A22 = a.W - 2.0f * (a.Mxx + a.Myy);

    *dmx = fmaf(A00, mx, fmaf(A01, my, fmaf(A02, mz, a.bsx)));
    *dmy = fmaf(A10, mx, fmaf(A11, my, fmaf(A12, mz, a.bsy)));
    *dmz = fmaf(A20, mx, fmaf(A21, my, fmaf(A22, mz, a.bsz)));

    float n   = sqrtf(a.qsw * a.qsw + a.qsx * a.qsx + a.qsy * a.qsy + a.qsz * a.qsz);
    float inv = 1.0f / fmaxf(n, 1e-8f);
    float bw = a.qsw * inv, bx = a.qsx * inv, by = a.qsy * inv, bz = a.qsz * inv;

    f32x4 r;
    r.x = bw * gw - bx * gx - by * gy - bz * gz;
    r.y = bw * gx + bx * gw + by * gz - bz * gy;
    r.z = bw * gy - bx * gz + by * gw + bz * gx;
    r.w = bw * gz + bx * gy - by * gx + bz * gw;
    *oq = r;
}

__device__ __forceinline__ void build_table(
    const float* __restrict__ ctrl_trans,
    const float* __restrict__ ctrl_rot,
    const float* __restrict__ ctrl_pos,
    float4* __restrict__ tbl, int K_TOTAL)
{
    for (int cp = threadIdx.x; cp < K_TOTAL; cp += blockDim.x) {
        float4 qv = ((const float4*)ctrl_rot)[cp];
        float qw = qv.x, qx = qv.y, qy = qv.z, qz = qv.w;
        float nn  = sqrtf(qw * qw + qx * qx + qy * qy + qz * qz);
        float inv = 1.0f / fmaxf(nn, 1e-8f);
        float w = qw * inv, x = qx * inv, y = qy * inv, z = qz * inv;
        float R00 = 1.0f - 2.0f * (y * y + z * z);
        float R01 = 2.0f * (x * y - w * z);
        float R02 = 2.0f * (x * z + w * y);
        float R10 = 2.0f * (x * y + w * z);
        float R11 = 1.0f - 2.0f * (x * x + z * z);
        float R12 = 2.0f * (y * z - w * x);
        float R20 = 2.0f * (x * z - w * y);
        float R21 = 2.0f * (y * z + w * x);
        float R22 = 1.0f - 2.0f * (x * x + y * y);
        float px = ctrl_pos[cp * 3 + 0];
        float py = ctrl_pos[cp * 3 + 1];
        float pz = ctrl_pos[cp * 3 + 2];
        float tx = ctrl_trans[cp * 3 + 0];
        float ty = ctrl_trans[cp * 3 + 1];
        float tz = ctrl_trans[cp * 3 + 2];
        tbl[cp]           = make_float4(w, x, y, z);
        tbl[K_TOTAL + cp] = make_float4(px + tx - (R00 * px + R01 * py + R02 * pz),
                                        py + ty - (R10 * px + R11 * py + R12 * pz),
                                        pz + tz - (R20 * px + R21 * py + R22 * pz),
                                        0.0f);
    }
}

// Fast path: K_NB=10, non-temporal streaming loads/stores.
__global__ __launch_bounds__(256) void deform_nt_kernel(
    const float* __restrict__ means,
    const float* __restrict__ quats,
    const float* __restrict__ weights,
    const float* __restrict__ ctrl_trans,
    const float* __restrict__ ctrl_rot,
    const float* __restrict__ ctrl_pos,
    const int*   __restrict__ indices,
    float* __restrict__ out_means,
    float* __restrict__ out_quats,
    int N, int K_TOTAL)
{
    extern __shared__ float4 tbl[];
    build_table(ctrl_trans, ctrl_rot, ctrl_pos, tbl, K_TOTAL);
    __syncthreads();

    long long i = (long long)blockIdx.x * blockDim.x + threadIdx.x;
    if (i >= N) return;

    // ---- non-temporal stream loads (single-use data: bypass L1) ----
    const i32x2* ip = (const i32x2*)(indices + i * 10);   // 40B row, 8B aligned
    const f32x2* wp = (const f32x2*)(weights + i * 10);
    i32x2 i01 = __builtin_nontemporal_load(ip + 0);
    i32x2 i23 = __builtin_nontemporal_load(ip + 1);
    i32x2 i45 = __builtin_nontemporal_load(ip + 2);
    i32x2 i67 = __builtin_nontemporal_load(ip + 3);
    i32x2 i89 = __builtin_nontemporal_load(ip + 4);
    f32x2 w01 = __builtin_nontemporal_load(wp + 0);
    f32x2 w23 = __builtin_nontemporal_load(wp + 1);
    f32x2 w45 = __builtin_nontemporal_load(wp + 2);
    f32x2 w67 = __builtin_nontemporal_load(wp + 3);
    f32x2 w89 = __builtin_nontemporal_load(wp + 4);

    float mx = __builtin_nontemporal_load(means + i * 3 + 0);
    float my = __builtin_nontemporal_load(means + i * 3 + 1);
    float mz = __builtin_nontemporal_load(means + i * 3 + 2);
    f32x4 gq = __builtin_nontemporal_load((const f32x4*)quats + i);

    Accum a; acc_init(a);
    acc_neighbor(a, tbl, K_TOTAL, i01.x, w01.x);
    acc_neighbor(a, tbl, K_TOTAL, i01.y, w01.y);
    acc_neighbor(a, tbl, K_TOTAL, i23.x, w23.x);
    acc_neighbor(a, tbl, K_TOTAL, i23.y, w23.y);
    acc_neighbor(a, tbl, K_TOTAL, i45.x, w45.x);
    acc_neighbor(a, tbl, K_TOTAL, i45.y, w45.y);
    acc_neighbor(a, tbl, K_TOTAL, i67.x, w67.x);
    acc_neighbor(a, tbl, K_TOTAL, i67.y, w67.y);
    acc_neighbor(a, tbl, K_TOTAL, i89.x, w89.x);
    acc_neighbor(a, tbl, K_TOTAL, i89.y, w89.y);

    float dx, dy, dz;
    f32x4 oq;
    acc_epilogue(a, mx, my, mz, gq.x, gq.y, gq.z, gq.w, &dx, &dy, &dz, &oq);

    // ---- non-temporal stores ----
    __builtin_nontemporal_store(dx, out_means + i * 3 + 0);
    __builtin_nontemporal_store(dy, out_means + i * 3 + 1);
    __builtin_nontemporal_store(dz, out_means + i * 3 + 2);
    __builtin_nontemporal_store(oq, (f32x4*)out_quats + i);
}

// Generic fallback: runtime K_NB, plain loads.
__global__ __launch_bounds__(256) void deform_generic_kernel(
    const float* __restrict__ means,
    const float* __restrict__ quats,
    const float* __restrict__ weights,
    const float* __restrict__ ctrl_trans,
    const float* __restrict__ ctrl_rot,
    const float* __restrict__ ctrl_pos,
    const int*   __restrict__ indices,
    float* __restrict__ out_means,
    float* __restrict__ out_quats,
    int N, int K_NB, int K_TOTAL)
{
    extern __shared__ float4 tbl[];
    build_table(ctrl_trans, ctrl_rot, ctrl_pos, tbl, K_TOTAL);
    __syncthreads();

    long long i = (long long)blockIdx.x * blockDim.x + threadIdx.x;
    if (i >= N) return;

    const int*   idx_row = indices + i * K_NB;
    const float* w_row   = weights + i * K_NB;
    Accum a; acc_init(a);
    for (int k = 0; k < K_NB; k++)
        acc_neighbor(a, tbl, K_TOTAL, idx_row[k], w_row[k]);

    float mx = means[i * 3 + 0];
    float my = means[i * 3 + 1];
    float mz = means[i * 3 + 2];
    float4 g4 = ((const float4*)quats)[i];
    float dx, dy, dz;
    f32x4 oq;
    acc_epilogue(a, mx, my, mz, g4.x, g4.y, g4.z, g4.w, &dx, &dy, &dz, &oq);
    out_means[i * 3 + 0] = dx;
    out_means[i * 3 + 1] = dy;
    out_means[i * 3 + 2] = dz;
    float4* oqp = (float4*)(out_quats + i * 4);
    *oqp = make_float4(oq.x, oq.y, oq.z, oq.w);
}

extern "C" void kernel_launch(void* const* d_in, const int* in_sizes, int n_in,
                              void* d_out, int out_size, void* d_ws, size_t ws_size,
                              hipStream_t stream) {
    const float* means      = (const float*)d_in[0];
    const float* quats      = (const float*)d_in[1];
    const float* weights    = (const float*)d_in[2];
    const float* ctrl_trans = (const float*)d_in[3];
    const float* ctrl_rot   = (const float*)d_in[4];
    const float* ctrl_pos   = (const float*)d_in[5];
    const int*   indices    = (const int*)d_in[6];

    int N       = in_sizes[0] / 3;
    int K_NB    = in_sizes[2] / N;       // weights is N*K_NB
    int K_TOTAL = in_sizes[3] / 3;       // ctrl_translations is K_TOTAL*3

    float* out_means = (float*)d_out;
    float* out_quats = (float*)d_out + (long long)N * 3;

    int block = 256;
    int grid  = (int)(((long long)N + block - 1) / block);
    size_t smem = (size_t)K_TOTAL * 2 * sizeof(float4);

    if (K_NB == 10) {
        deform_nt_kernel<<<grid, block, smem, stream>>>(
            means, quats, weights, ctrl_trans, ctrl_rot, ctrl_pos, indices,
            out_means, out_quats, N, K_TOTAL);
    } else {
        deform_generic_kernel<<<grid, block, smem, stream>>>(
            means, quats, weights, ctrl_trans, ctrl_rot, ctrl_pos, indices,
            out_means, out_quats, N, K_NB, K_TOTAL);
    }
}

// Round 7
// 148.536 us; speedup vs baseline: 1.0741x; 1.0741x over previous
//
#include <hip/hip_runtime.h>
#include <math.h>

// Deformation4D: N=1M gaussians, K_NB=10 neighbors, K_TOTAL=300 control points.
//
// v8 (FINAL CANDIDATE = revert to measured-best config).
// Session ledger: seven structural variants (43.4-46.7us kernel) varied LDS
// gather bytes (2x), bank conflicts (1.9x), VMEM request shape (scalar <->
// fully coalesced), occupancy (3x), wave count (2.5x), ILP/pipelining,
// dispatch count (1<->2), and HBM traffic (82<->122MB via nt) -- ALL neutral
// on time; no pipe >33% busy. Conclusion: the ~44us kernel is at a
// latency/clock-governed floor for this dispatch size, not a pipe limit.
// v7's nt loads REGRESSED HBM fetch (+75%: lost cross-iteration L3
// retention) at zero time change -- final proof the fetch path isn't the
// wall, and reason to revert them.
//
// Best-measured structure kept:
// - single dispatch, fused in-block table build (2-dispatch split was
//   neutral-to-worse: serialized launch latency).
// - monomial algebra: sum_k w_k R(q_hat_k) is linear in M = sum w q q^T,
//   so per neighbor we gather only q_hat(16B)+b(16B), b = p + t - R*p, and
//   rebuild sum(wR) once in the epilogue. Halves LDS gather traffic vs
//   gathering R directly.
// - LDS table de-interleaved at 16B stride (q at tbl[cp], b at tbl[K+cp]):
//   8 bank-groups for random cp (32B stride gave 4 groups and doubled
//   per-read conflicts -- measured in v3).
// - 1 gaussian/thread, full grid, plain loads/stores (lowest VGPR=44,
//   best L3 retention, same time as every fancier variant).

struct Accum {
    float W;
    float Mxx, Myy, Mzz, Mxy, Mxz, Myz, Mwx, Mwy, Mwz;
    float qsw, qsx, qsy, qsz;
    float bsx, bsy, bsz;
};

__device__ __forceinline__ void acc_init(Accum& a) {
    a.W = 0.0f;
    a.Mxx = a.Myy = a.Mzz = 0.0f;
    a.Mxy = a.Mxz = a.Myz = 0.0f;
    a.Mwx = a.Mwy = a.Mwz = 0.0f;
    a.qsw = a.qsx = a.qsy = a.qsz = 0.0f;
    a.bsx = a.bsy = a.bsz = 0.0f;
}

__device__ __forceinline__ void acc_neighbor(Accum& a, const float4* __restrict__ tbl,
                                             int K_TOTAL, int cp, float w) {
    float4 q = tbl[cp];             // (w,x,y,z) normalized; 16B stride
    float4 b = tbl[K_TOTAL + cp];   // (bx,by,bz,_)
    float tw = w * q.x, tx = w * q.y, ty = w * q.z, tz = w * q.w;
    a.W += w;
    a.Mxx = fmaf(tx, q.y, a.Mxx);
    a.Myy = fmaf(ty, q.z, a.Myy);
    a.Mzz = fmaf(tz, q.w, a.Mzz);
    a.Mxy = fmaf(tx, q.z, a.Mxy);
    a.Mxz = fmaf(tx, q.w, a.Mxz);
    a.Myz = fmaf(ty, q.w, a.Myz);
    a.Mwx = fmaf(tw, q.y, a.Mwx);
    a.Mwy = fmaf(tw, q.z, a.Mwy);
    a.Mwz = fmaf(tw, q.w, a.Mwz);
    a.qsw += tw; a.qsx += tx; a.qsy += ty; a.qsz += tz;
    a.bsx = fmaf(w, b.x, a.bsx);
    a.bsy = fmaf(w, b.y, a.bsy);
    a.bsz = fmaf(w, b.z, a.bsz);
}

__device__ __forceinline__ void acc_epilogue(const Accum& a,
                                             float mx, float my, float mz,
                                             float gw, float gx, float gy, float gz,
                                             float* dmx, float* dmy, float* dmz,
                                             float4* oq) {
    float A00 = a.W - 2.0f * (a.Myy + a.Mzz);
    float A01 = 2.0f * (a.Mxy - a.Mwz);
    float A02 = 2.0f * (a.Mxz + a.Mwy);
    float A10 = 2.0f * (a.Mxy + a.Mwz);
    float A11 = a.W - 2.0f * (a.Mxx + a.Mzz);
    float A12 = 2.0f * (a.Myz - a.Mwx);
    float A20 = 2.0f * (a.Mxz - a.Mwy);
    float A21 = 2.0f * (a.Myz + a.Mwx);
    float A22 = a.W - 2.0f * (a.Mxx + a.Myy);

    *dmx = fmaf(A00, mx, fmaf(A01, my, fmaf(A02, mz, a.bsx)));
    *dmy = fmaf(A10, mx, fmaf(A11, my, fmaf(A12, mz, a.bsy)));
    *dmz = fmaf(A20, mx, fmaf(A21, my, fmaf(A22, mz, a.bsz)));

    float n   = sqrtf(a.qsw * a.qsw + a.qsx * a.qsx + a.qsy * a.qsy + a.qsz * a.qsz);
    float inv = 1.0f / fmaxf(n, 1e-8f);
    float bw = a.qsw * inv, bx = a.qsx * inv, by = a.qsy * inv, bz = a.qsz * inv;

    oq->x = bw * gw - bx * gx - by * gy - bz * gz;
    oq->y = bw * gx + bx * gw + by * gz - bz * gy;
    oq->z = bw * gy - bx * gz + by * gw + bz * gx;
    oq->w = bw * gz + bx * gy - by * gx + bz * gw;
}

__device__ __forceinline__ void build_table(
    const float* __restrict__ ctrl_trans,
    const float* __restrict__ ctrl_rot,
    const float* __restrict__ ctrl_pos,
    float4* __restrict__ tbl, int K_TOTAL)
{
    for (int cp = threadIdx.x; cp < K_TOTAL; cp += blockDim.x) {
        float4 qv = ((const float4*)ctrl_rot)[cp];
        float qw = qv.x, qx = qv.y, qy = qv.z, qz = qv.w;
        float nn  = sqrtf(qw * qw + qx * qx + qy * qy + qz * qz);
        float inv = 1.0f / fmaxf(nn, 1e-8f);
        float w = qw * inv, x = qx * inv, y = qy * inv, z = qz * inv;
        float R00 = 1.0f - 2.0f * (y * y + z * z);
        float R01 = 2.0f * (x * y - w * z);
        float R02 = 2.0f * (x * z + w * y);
        float R10 = 2.0f * (x * y + w * z);
        float R11 = 1.0f - 2.0f * (x * x + z * z);
        float R12 = 2.0f * (y * z - w * x);
        float R20 = 2.0f * (x * z - w * y);
        float R21 = 2.0f * (y * z + w * x);
        float R22 = 1.0f - 2.0f * (x * x + y * y);
        float px = ctrl_pos[cp * 3 + 0];
        float py = ctrl_pos[cp * 3 + 1];
        float pz = ctrl_pos[cp * 3 + 2];
        float tx = ctrl_trans[cp * 3 + 0];
        float ty = ctrl_trans[cp * 3 + 1];
        float tz = ctrl_trans[cp * 3 + 2];
        tbl[cp]           = make_float4(w, x, y, z);
        tbl[K_TOTAL + cp] = make_float4(px + tx - (R00 * px + R01 * py + R02 * pz),
                                        py + ty - (R10 * px + R11 * py + R12 * pz),
                                        pz + tz - (R20 * px + R21 * py + R22 * pz),
                                        0.0f);
    }
}

// Fast path: K_NB=10 compile-time unrolled.
__global__ __launch_bounds__(256) void deform_kernel(
    const float* __restrict__ means,
    const float* __restrict__ quats,
    const float* __restrict__ weights,
    const float* __restrict__ ctrl_trans,
    const float* __restrict__ ctrl_rot,
    const float* __restrict__ ctrl_pos,
    const int*   __restrict__ indices,
    float* __restrict__ out_means,
    float* __restrict__ out_quats,
    int N, int K_TOTAL)
{
    extern __shared__ float4 tbl[];
    build_table(ctrl_trans, ctrl_rot, ctrl_pos, tbl, K_TOTAL);
    __syncthreads();

    long long i = (long long)blockIdx.x * blockDim.x + threadIdx.x;
    if (i >= N) return;

    // 40B rows, 8B aligned -> int2/float2 vector loads
    const int2*   ip = (const int2*)(indices + i * 10);
    const float2* wp = (const float2*)(weights + i * 10);
    int2   i01 = ip[0], i23 = ip[1], i45 = ip[2], i67 = ip[3], i89 = ip[4];
    float2 w01 = wp[0], w23 = wp[1], w45 = wp[2], w67 = wp[3], w89 = wp[4];

    float mx = means[i * 3 + 0];
    float my = means[i * 3 + 1];
    float mz = means[i * 3 + 2];
    float4 gq = ((const float4*)quats)[i];

    Accum a; acc_init(a);
    acc_neighbor(a, tbl, K_TOTAL, i01.x, w01.x);
    acc_neighbor(a, tbl, K_TOTAL, i01.y, w01.y);
    acc_neighbor(a, tbl, K_TOTAL, i23.x, w23.x);
    acc_neighbor(a, tbl, K_TOTAL, i23.y, w23.y);
    acc_neighbor(a, tbl, K_TOTAL, i45.x, w45.x);
    acc_neighbor(a, tbl, K_TOTAL, i45.y, w45.y);
    acc_neighbor(a, tbl, K_TOTAL, i67.x, w67.x);
    acc_neighbor(a, tbl, K_TOTAL, i67.y, w67.y);
    acc_neighbor(a, tbl, K_TOTAL, i89.x, w89.x);
    acc_neighbor(a, tbl, K_TOTAL, i89.y, w89.y);

    float dx, dy, dz;
    float4 oq;
    acc_epilogue(a, mx, my, mz, gq.x, gq.y, gq.z, gq.w, &dx, &dy, &dz, &oq);

    out_means[i * 3 + 0] = dx;
    out_means[i * 3 + 1] = dy;
    out_means[i * 3 + 2] = dz;
    ((float4*)out_quats)[i] = oq;
}

// Generic fallback: runtime K_NB.
__global__ __launch_bounds__(256) void deform_generic_kernel(
    const float* __restrict__ means,
    const float* __restrict__ quats,
    const float* __restrict__ weights,
    const float* __restrict__ ctrl_trans,
    const float* __restrict__ ctrl_rot,
    const float* __restrict__ ctrl_pos,
    const int*   __restrict__ indices,
    float* __restrict__ out_means,
    float* __restrict__ out_quats,
    int N, int K_NB, int K_TOTAL)
{
    extern __shared__ float4 tbl[];
    build_table(ctrl_trans, ctrl_rot, ctrl_pos, tbl, K_TOTAL);
    __syncthreads();

    long long i = (long long)blockIdx.x * blockDim.x + threadIdx.x;
    if (i >= N) return;

    const int*   idx_row = indices + i * K_NB;
    const float* w_row   = weights + i * K_NB;
    Accum a; acc_init(a);
    for (int k = 0; k < K_NB; k++)
        acc_neighbor(a, tbl, K_TOTAL, idx_row[k], w_row[k]);

    float mx = means[i * 3 + 0];
    float my = means[i * 3 + 1];
    float mz = means[i * 3 + 2];
    float4 gq = ((const float4*)quats)[i];
    float dx, dy, dz;
    float4 oq;
    acc_epilogue(a, mx, my, mz, gq.x, gq.y, gq.z, gq.w, &dx, &dy, &dz, &oq);
    out_means[i * 3 + 0] = dx;
    out_means[i * 3 + 1] = dy;
    out_means[i * 3 + 2] = dz;
    ((float4*)out_quats)[i] = oq;
}

extern "C" void kernel_launch(void* const* d_in, const int* in_sizes, int n_in,
                              void* d_out, int out_size, void* d_ws, size_t ws_size,
                              hipStream_t stream) {
    const float* means      = (const float*)d_in[0];
    const float* quats      = (const float*)d_in[1];
    const float* weights    = (const float*)d_in[2];
    const float* ctrl_trans = (const float*)d_in[3];
    const float* ctrl_rot   = (const float*)d_in[4];
    const float* ctrl_pos   = (const float*)d_in[5];
    const int*   indices    = (const int*)d_in[6];

    int N       = in_sizes[0] / 3;
    int K_NB    = in_sizes[2] / N;       // weights is N*K_NB
    int K_TOTAL = in_sizes[3] / 3;       // ctrl_translations is K_TOTAL*3

    float* out_means = (float*)d_out;
    float* out_quats = (float*)d_out + (long long)N * 3;

    int block = 256;
    int grid  = (int)(((long long)N + block - 1) / block);
    size_t smem = (size_t)K_TOTAL * 2 * sizeof(float4);

    if (K_NB == 10) {
        deform_kernel<<<grid, block, smem, stream>>>(
            means, quats, weights, ctrl_trans, ctrl_rot, ctrl_pos, indices,
            out_means, out_quats, N, K_TOTAL);
    } else {
        deform_generic_kernel<<<grid, block, smem, stream>>>(
            means, quats, weights, ctrl_trans, ctrl_rot, ctrl_pos, indices,
            out_means, out_quats, N, K_NB, K_TOTAL);
    }
}